// Round 6
// baseline (1474.423 us; speedup 1.0000x reference)
//
#include <hip/hip_runtime.h>
#include <hip/hip_fp16.h>
#include <stdint.h>
#include <stddef.h>

typedef _Float16 f16;
typedef __attribute__((ext_vector_type(4))) _Float16 f16x4;
typedef __attribute__((ext_vector_type(8))) _Float16 f16x8;
typedef __attribute__((ext_vector_type(4))) float f32x4;
typedef __attribute__((ext_vector_type(16))) float f32x16;

// async global->LDS, 16B per lane. LDS dest is wave-uniform base + lane*16.
__device__ __forceinline__ void gld_lds16(const void* g, void* l) {
  __builtin_amdgcn_global_load_lds((const __attribute__((address_space(1))) void*)g,
                                   (__attribute__((address_space(3))) void*)l, 16, 0, 0);
}

__device__ __forceinline__ void vm0() {
  __asm__ volatile("s_waitcnt vmcnt(0)" ::: "memory");
}
__device__ __forceinline__ void lgkm0() {
  __asm__ volatile("s_waitcnt lgkmcnt(0)" ::: "memory");
}

// ---------------- fused cast f32 -> f16 for all 5 tensors ----------------
__global__ void cast_all(const float* __restrict__ x, const float* __restrict__ wq,
                         const float* __restrict__ wk, const float* __restrict__ wv,
                         const float* __restrict__ wo, f16* __restrict__ xh,
                         f16* __restrict__ wqh, f16* __restrict__ wkh,
                         f16* __restrict__ wvh, f16* __restrict__ woh) {
  int i = blockIdx.x * blockDim.x + threadIdx.x;
  const float* in;
  f16* out;
  int j = i;
  if (j < 4194304) { in = x; out = xh; }
  else if ((j -= 4194304) < 4194304) { in = wq; out = wqh; }
  else if ((j -= 4194304) < 1048576) { in = wk; out = wkh; }
  else if ((j -= 1048576) < 1048576) { in = wv; out = wvh; }
  else { j -= 1048576; in = wo; out = woh; }
  float4 v = ((const float4*)in)[j];
  f16x4 h;
  h[0] = (f16)v.x; h[1] = (f16)v.y; h[2] = (f16)v.z; h[3] = (f16)v.w;
  *(f16x4*)(out + (size_t)j * 4) = h;
}

// ---------------- GEMM core: C(256 x NF*128) = A(256xK) * B(NF*128 x K)^T, K=4096 ----
// 32x32x16 MFMA (2x FLOP per LDS byte vs 16x16x32), 8 waves 2x4, ring-2 LDS, BK=64,
// one barrier + vmcnt(0) per tile (STAGE(t+1) hides under the tile's MFMAs).
// 3-bit XOR granule swizzle keeps fragment ds_read_b128 conflict-free.
template <int NF>
__device__ __forceinline__ void gemm_core(const f16* __restrict__ Ab,
                                          const f16* __restrict__ Bb,
                                          f16* __restrict__ lds,
                                          f32x16 acc[4][NF]) {
  constexpr int BN = NF * 128;
  constexpr int S = 16384 + BN * 64;  // f16 stride of one ring buffer
  constexpr int BU = BN / 64;         // B granule-chunks per thread
  const int tid = threadIdx.x, ln = tid & 63, wv = tid >> 6;
  const int wr = wv >> 2, wc = wv & 3;
  const int l31 = ln & 31, h32 = ln >> 5;
  const int x7 = l31 & 7;
#pragma unroll
  for (int mi = 0; mi < 4; ++mi)
#pragma unroll
    for (int ni = 0; ni < NF; ++ni)
#pragma unroll
      for (int r = 0; r < 16; ++r) acc[mi][ni][r] = 0.f;

  // staging source offsets (f16 elements): physical granule P -> unswizzled global col
  int sA[4], sB[BU];
#pragma unroll
  for (int u = 0; u < 4; ++u) {
    int P = u * 512 + tid;
    sA[u] = (P >> 3) * 4096 + (((P & 7) ^ ((P >> 3) & 7)) * 8);
  }
#pragma unroll
  for (int u = 0; u < BU; ++u) {
    int P = u * 512 + tid;
    sB[u] = (P >> 3) * 4096 + (((P & 7) ^ ((P >> 3) & 7)) * 8);
  }
  // fragment row bases (f16 index into buffer); row&7 == l31&7 for all frags
  int rA[4], rB[NF];
#pragma unroll
  for (int mi = 0; mi < 4; ++mi) rA[mi] = (wr * 128 + mi * 32 + l31) * 64;
#pragma unroll
  for (int ni = 0; ni < NF; ++ni) rB[ni] = 16384 + (wc * (NF * 32) + ni * 32 + l31) * 64;

#define STAGE(BUF, K0)                                                        \
  {                                                                           \
    _Pragma("unroll") for (int u = 0; u < 4; ++u) {                           \
      gld_lds16(Ab + sA[u] + (K0), lds + (BUF) + (u * 512 + wv * 64) * 8);    \
    }                                                                         \
    _Pragma("unroll") for (int u = 0; u < BU; ++u) {                          \
      gld_lds16(Bb + sB[u] + (K0),                                            \
                lds + (BUF) + 16384 + (u * 512 + wv * 64) * 8);               \
    }                                                                         \
  }

#define TILE_COMPUTE(BUF)                                                     \
  _Pragma("unroll") for (int ks = 0; ks < 4; ++ks) {                          \
    f16x8 af[4];                                                              \
    f16x8 bf[NF];                                                             \
    int gk = ((ks * 2 + h32) ^ x7) * 8;                                       \
    _Pragma("unroll") for (int mi = 0; mi < 4; ++mi) {                        \
      af[mi] = *(const f16x8*)&lds[(BUF) + rA[mi] + gk];                      \
    }                                                                         \
    _Pragma("unroll") for (int ni = 0; ni < NF; ++ni) {                       \
      bf[ni] = *(const f16x8*)&lds[(BUF) + rB[ni] + gk];                      \
    }                                                                         \
    __builtin_amdgcn_s_setprio(1);                                            \
    _Pragma("unroll") for (int mi = 0; mi < 4; ++mi) {                        \
      _Pragma("unroll") for (int ni = 0; ni < NF; ++ni) {                     \
        acc[mi][ni] = __builtin_amdgcn_mfma_f32_32x32x16_f16(                 \
            af[mi], bf[ni], acc[mi][ni], 0, 0, 0);                            \
      }                                                                       \
    }                                                                         \
    __builtin_amdgcn_s_setprio(0);                                            \
  }

#define SYNC()                                                                \
  __builtin_amdgcn_sched_barrier(0);                                          \
  vm0();                                                                      \
  __builtin_amdgcn_s_barrier();                                               \
  __builtin_amdgcn_sched_barrier(0);

  int cur = 0, nxt = S;
  STAGE(cur, 0);
  SYNC();
#pragma unroll 1
  for (int t = 0; t < 63; ++t) {
    STAGE(nxt, (t + 1) * 64);
    TILE_COMPUTE(cur);
    SYNC();
    int tmp = cur; cur = nxt; nxt = tmp;
  }
  TILE_COMPUTE(cur);

#undef STAGE
#undef TILE_COMPUTE
#undef SYNC
}

// ---------------- fused QKV projection ----------------
// 256 blocks (16 M x 16 N of 384), one per CU, single round. wqh/wkh/wvh are contiguous
// in the workspace -> B panels read linearly from wqh even when straddling Q/K/V.
__global__ __launch_bounds__(512, 2) void gemm_qkv(
    const f16* __restrict__ xh, const f16* __restrict__ wcat,
    f16* __restrict__ qh, f16* __restrict__ kh, f16* __restrict__ vt) {
  __shared__ __align__(16) f16 lds[81920];  // 160 KiB: 2 x (A 32K + B 48K)
  const int id = blockIdx.x;
  const int swz = (id & 7) * 32 + (id >> 3);  // 256 = 8 XCD * 32 (bijective)
  const int bx = swz & 15, by = swz >> 4;
  f32x16 acc[4][3];
  gemm_core<3>(xh + (size_t)by * 256 * 4096, wcat + (size_t)bx * 384 * 4096, lds, acc);
  const int tid = threadIdx.x, ln = tid & 63, wv = tid >> 6;
  const int wr = wv >> 2, wc = wv & 3;
  const int l31 = ln & 31, h32 = ln >> 5;
#pragma unroll
  for (int mi = 0; mi < 4; ++mi)
#pragma unroll
    for (int ni = 0; ni < 3; ++ni) {
      int gc = bx * 384 + wc * 96 + ni * 32;  // frag col base (wave-uniform)
#pragma unroll
      for (int g = 0; g < 4; ++g) {
        int row = by * 256 + wr * 128 + mi * 32 + h32 * 4 + g * 8;  // token of reg 4g
        if (gc < 4096) {
#pragma unroll
          for (int r2 = 0; r2 < 4; ++r2)
            qh[(size_t)(row + r2) * 4096 + gc + l31] = (f16)acc[mi][ni][g * 4 + r2];
        } else if (gc < 5120) {
#pragma unroll
          for (int r2 = 0; r2 < 4; ++r2)
            kh[(size_t)(row + r2) * 1024 + (gc - 4096) + l31] = (f16)acc[mi][ni][g * 4 + r2];
        } else {
          f16x4 v4;
#pragma unroll
          for (int r2 = 0; r2 < 4; ++r2) v4[r2] = (f16)acc[mi][ni][g * 4 + r2];
          int vcol = gc + l31 - 5120;
          int kv = vcol >> 7, d = vcol & 127;
          int bbv = row >> 11, sl = row & 2047;  // 4 consecutive tokens, same batch
          *(f16x4*)&vt[(((size_t)bbv * 8 + kv) * 128 + d) * 2048 + sl] = v4;
        }
      }
    }
}

// ---------------- RoPE in-place on Q and K (16B per thread) ----------------
__global__ void rope_qk(f16* __restrict__ qh, f16* __restrict__ kh,
                        const float* __restrict__ fc, const float* __restrict__ fs) {
  int i = blockIdx.x * blockDim.x + threadIdx.x;  // granule = 8 f16 = 4 rot pairs
  const int QG = 4096 * 32 * 16;
  f16* ptr;
  int sl, p0;
  if (i < QG) {
    int g = i & 15, head = (i >> 4) & 31, tok = i >> 9;
    sl = tok & 2047; p0 = g * 4;
    ptr = qh + (size_t)tok * 4096 + head * 128 + g * 8;
  } else {
    int j = i - QG;
    int g = j & 15, head = (j >> 4) & 7, tok = j >> 7;
    sl = tok & 2047; p0 = g * 4;
    ptr = kh + (size_t)tok * 1024 + head * 128 + g * 8;
  }
  f16x8 v = *(f16x8*)ptr;
  float4 c = *(const float4*)&fc[sl * 64 + p0];
  float4 s = *(const float4*)&fs[sl * 64 + p0];
  f16x8 o;
  o[0] = (f16)((float)v[0] * c.x - (float)v[1] * s.x);
  o[1] = (f16)((float)v[0] * s.x + (float)v[1] * c.x);
  o[2] = (f16)((float)v[2] * c.y - (float)v[3] * s.y);
  o[3] = (f16)((float)v[2] * s.y + (float)v[3] * c.y);
  o[4] = (f16)((float)v[4] * c.z - (float)v[5] * s.z);
  o[5] = (f16)((float)v[4] * s.z + (float)v[5] * c.z);
  o[6] = (f16)((float)v[6] * c.w - (float)v[7] * s.w);
  o[7] = (f16)((float)v[6] * s.w + (float)v[7] * c.w);
  *(f16x8*)ptr = o;
}

// ---------------- causal GQA flash attention (transposed S/O formulation) ----------------
// grid (32 qtiles, 32 heads, 2 batch), 4 waves, each wave a 16-query strip (q = lane&15).
// S^T = K Q^T  (lane owns query col q=c16 -> in-lane softmax), O^T = V^T P^T.
// NO K/V LDS staging: K (8 MiB) and V (8 MiB) are L2/L3-resident and reused 4x within
// a block (L1 absorbs); fragments are read directly from global (each wave instruction
// touches 16 rows x one full 64B sector -> no wasted sectors). This removes ALL
// barriers from the loop (only per-wave Pl LDS with lgkm ordering remains), drops
// LDS 40KB -> 8KB, and lets up to 8 blocks/CU hide latency via TLP.
__global__ __launch_bounds__(256, 4) void attn(
    const f16* __restrict__ qh, const f16* __restrict__ kh,
    const f16* __restrict__ vt, f16* __restrict__ ao) {
  __shared__ __align__(16) f16 Pl[4][16 * 64]; // per-wave P [q][k], granule-swizzled g^(q&7)
  const int qt = 31 - blockIdx.x;  // longest blocks dispatch first
  const int h = blockIdx.y, bb = blockIdx.z;
  const int kvh = h >> 2;
  const int tid = threadIdx.x, ln = tid & 63, wv = tid >> 6;
  const int quad = ln >> 4, c16 = ln & 15;

  // Q fragment (A/B layout identical): lane holds Q[q=strip row c16][d = ks*32+quad*8+j]
  f16x8 Qf[4];
  {
    size_t qbase = ((size_t)(bb * 2048 + qt * 64 + wv * 16 + c16)) * 4096 + h * 128;
#pragma unroll
    for (int ks = 0; ks < 4; ++ks)
      Qf[ks] = *(const f16x8*)&qh[qbase + ks * 32 + quad * 8];
  }
  float m_run = -INFINITY, l_run = 0.f;
  f32x4 Ot[8];  // O^T tiles over d; lane col = q
#pragma unroll
  for (int n = 0; n < 8; ++n) { f32x4 z = {0.f, 0.f, 0.f, 0.f}; Ot[n] = z; }
  const float scale = 0.08838834764831843f;  // 1/sqrt(128)
  const int qg = qt * 64 + wv * 16 + c16;    // this lane's global query index
  const int swp = ((quad ^ (c16 & 7)) * 8);         // Pl read swizzle, ks=0
  const int swp1 = (((4 + quad) ^ (c16 & 7)) * 8);  // ks=1

  // global bases: K rows (this lane reads row tn*16+c16 of each tile), V^T rows (d)
  const f16* kb = kh + ((size_t)(bb * 2048 + c16)) * 1024 + kvh * 128;
  const f16* vb = vt + ((size_t)(bb * 8 + kvh) * 128 + c16) * 2048;

  for (int t = 0; t <= qt; ++t) {
    // S^T(64x16 per wave): Sa[tn] = K-tile(tn) x Q^T; D[k'=quad*4+r][q=c16]
    const f16* kt = kb + (size_t)t * 64 * 1024;
    f32x4 Sa[4];
#pragma unroll
    for (int tn = 0; tn < 4; ++tn) {
      f32x4 z = {0.f, 0.f, 0.f, 0.f};
      Sa[tn] = z;
#pragma unroll
      for (int ks = 0; ks < 4; ++ks) {
        f16x8 kf = *(const f16x8*)&kt[(size_t)tn * 16 * 1024 + (ks * 4 + quad) * 8];
        Sa[tn] = __builtin_amdgcn_mfma_f32_16x16x32_f16(kf, Qf[ks], Sa[tn], 0, 0, 0);
      }
    }

    // scale + causal mask (diagonal tile only)
#pragma unroll
    for (int tn = 0; tn < 4; ++tn)
#pragma unroll
      for (int r = 0; r < 4; ++r) Sa[tn][r] *= scale;
    if (t == qt) {
#pragma unroll
      for (int tn = 0; tn < 4; ++tn) {
        int kbase2 = t * 64 + tn * 16 + quad * 4;
#pragma unroll
        for (int r = 0; r < 4; ++r)
          if (kbase2 + r > qg) Sa[tn][r] = -INFINITY;
      }
    }

    // online softmax: per-lane (one q per lane), 2 shuffles per reduction
    float mm = -INFINITY;
#pragma unroll
    for (int tn = 0; tn < 4; ++tn)
#pragma unroll
      for (int r = 0; r < 4; ++r) mm = fmaxf(mm, Sa[tn][r]);
    mm = fmaxf(mm, __shfl_xor(mm, 16, 64));
    mm = fmaxf(mm, __shfl_xor(mm, 32, 64));
    float mn = fmaxf(m_run, mm);
    float alpha = __expf(m_run - mn);
    m_run = mn;
    float rsum = 0.f;
#pragma unroll
    for (int tn = 0; tn < 4; ++tn)
#pragma unroll
      for (int r = 0; r < 4; ++r) {
        float p = __expf(Sa[tn][r] - mn);
        Sa[tn][r] = p;
        rsum += p;
      }
    rsum += __shfl_xor(rsum, 16, 64);
    rsum += __shfl_xor(rsum, 32, 64);
    l_run = l_run * alpha + rsum;

    // P^T (C-layout) -> Pl[q][k] (8B packed, swizzled); per-wave, same-wave consumer
#pragma unroll
    for (int tn = 0; tn < 4; ++tn) {
      f16x4 pk;
#pragma unroll
      for (int r = 0; r < 4; ++r) pk[r] = (f16)Sa[tn][r];
      int g = tn * 2 + (quad >> 1);
      *(f16x4*)&Pl[wv][c16 * 64 + ((g ^ (c16 & 7)) * 8) + (quad & 1) * 4] = pk;
    }

    // rescale O (alpha is a per-lane scalar)
#pragma unroll
    for (int n = 0; n < 8; ++n)
#pragma unroll
      for (int r = 0; r < 4; ++r) Ot[n][r] *= alpha;

    lgkm0();  // P writes -> P reads (same wave)

    // O^T += V^T P^T : A = V^T fragments direct from global, B = rows of Pl[q][k]
    {
      f16x8 pf0 = *(const f16x8*)&Pl[wv][c16 * 64 + swp];
      f16x8 pf1 = *(const f16x8*)&Pl[wv][c16 * 64 + swp1];
      const f16* vtl = vb + t * 64;
#pragma unroll
      for (int n = 0; n < 8; ++n) {
        const f16* vd = vtl + (size_t)n * 16 * 2048;
        f16x8 vf0 = *(const f16x8*)&vd[quad * 8];
        Ot[n] = __builtin_amdgcn_mfma_f32_16x16x32_f16(vf0, pf0, Ot[n], 0, 0, 0);
        f16x8 vf1 = *(const f16x8*)&vd[32 + quad * 8];
        Ot[n] = __builtin_amdgcn_mfma_f32_16x16x32_f16(vf1, pf1, Ot[n], 0, 0, 0);
      }
    }
    // no barrier: waves are fully independent
  }

  // epilogue: O = O^T normalized; lane writes 4 contiguous d per tile (8B stores)
  float inv = 1.0f / l_run;
  size_t token = (size_t)(bb * 2048 + qt * 64 + wv * 16 + c16);
#pragma unroll
  for (int n = 0; n < 8; ++n) {
    f16x4 o;
#pragma unroll
    for (int r = 0; r < 4; ++r) o[r] = (f16)(Ot[n][r] * inv);
    *(f16x4*)&ao[token * 4096 + h * 128 + n * 16 + quad * 4] = o;
  }
}

// ---------------- output projection: out = ao @ wo^T (fp32 out) ----------------
__global__ __launch_bounds__(512, 2) void gemm_out(
    const f16* __restrict__ ao, const f16* __restrict__ woh, float* __restrict__ out) {
  __shared__ __align__(16) f16 lds[65536];  // 128 KiB: 2 x (A 32K + B 32K)
  const int id = blockIdx.x;
  const int swz = (id & 7) * 32 + (id >> 3);  // 256 = 8 XCD * 32 (bijective)
  const int bx = swz & 15, by = swz >> 4;
  f32x16 acc[4][2];
  gemm_core<2>(ao + (size_t)by * 256 * 4096, woh + (size_t)bx * 256 * 4096, lds, acc);
  const int tid = threadIdx.x, ln = tid & 63, wv = tid >> 6;
  const int wr = wv >> 2, wc = wv & 3;
  const int l31 = ln & 31, h32 = ln >> 5;
#pragma unroll
  for (int mi = 0; mi < 4; ++mi)
#pragma unroll
    for (int ni = 0; ni < 2; ++ni) {
      int col = bx * 256 + wc * 64 + ni * 32 + l31;
#pragma unroll
      for (int g = 0; g < 4; ++g) {
        int row = by * 256 + wr * 128 + mi * 32 + h32 * 4 + g * 8;
#pragma unroll
        for (int r2 = 0; r2 < 4; ++r2)
          out[(size_t)(row + r2) * 4096 + col] = acc[mi][ni][g * 4 + r2];
      }
    }
}

// ---------------- launch ----------------
extern "C" void kernel_launch(void* const* d_in, const int* in_sizes, int n_in,
                              void* d_out, int out_size, void* d_ws, size_t ws_size,
                              hipStream_t stream) {
  const float* x  = (const float*)d_in[0];
  const float* wq = (const float*)d_in[1];
  const float* wk = (const float*)d_in[2];
  const float* wv = (const float*)d_in[3];
  const float* wo = (const float*)d_in[4];
  const float* fc = (const float*)d_in[5];
  const float* fs = (const float*)d_in[6];
  float* out = (float*)d_out;

  char* ws = (char*)d_ws;
  f16* xh  = (f16*)(ws + 0);          // 32 MiB: x fp16 [4096][4096]
  f16* wqh = (f16*)(ws + 33554432);   // 32 MiB (wqh,wkh,wvh contiguous = wcat[6144][4096])
  f16* wkh = (f16*)(ws + 67108864);   // 8 MiB
  f16* wvh = (f16*)(ws + 75497472);   // 8 MiB
  f16* woh = (f16*)(ws + 83886080);   // 32 MiB
  f16* qh  = (f16*)(ws + 117440512);  // 32 MiB: Q [4096][4096]
  f16* kh  = (f16*)(ws + 150994944);  // 8 MiB:  K [4096][1024]
  f16* vt  = (f16*)(ws + 159383552);  // 8 MiB:  V^T [2][8][128][2048]
  f16* ao  = (f16*)(ws + 167772160);  // 32 MiB: attn out [4096][4096]

  cast_all<<<57344, 256, 0, stream>>>(x, wq, wk, wv, wo, xh, wqh, wkh, wvh, woh);
  gemm_qkv<<<256, 512, 0, stream>>>(xh, wqh, qh, kh, vt);
  rope_qk<<<10240, 256, 0, stream>>>(qh, kh, fc, fs);
  attn<<<dim3(32, 32, 2), 256, 0, stream>>>(qh, kh, vt, ao);
  gemm_out<<<256, 512, 0, stream>>>(ao, woh, out);
}

// Round 7
// 775.592 us; speedup vs baseline: 1.9010x; 1.9010x over previous
//
#include <hip/hip_runtime.h>
#include <hip/hip_fp16.h>
#include <stdint.h>
#include <stddef.h>

typedef _Float16 f16;
typedef __attribute__((ext_vector_type(4))) _Float16 f16x4;
typedef __attribute__((ext_vector_type(8))) _Float16 f16x8;
typedef __attribute__((ext_vector_type(4))) float f32x4;
typedef __attribute__((ext_vector_type(16))) float f32x16;

// async global->LDS, 16B per lane. LDS dest is wave-uniform base + lane*16.
__device__ __forceinline__ void gld_lds16(const void* g, void* l) {
  __builtin_amdgcn_global_load_lds((const __attribute__((address_space(1))) void*)g,
                                   (__attribute__((address_space(3))) void*)l, 16, 0, 0);
}

__device__ __forceinline__ void vm0() {
  __asm__ volatile("s_waitcnt vmcnt(0)" ::: "memory");
}
__device__ __forceinline__ void lgkm0() {
  __asm__ volatile("s_waitcnt lgkmcnt(0)" ::: "memory");
}

// ---------------- fused cast f32 -> f16 for all 5 tensors ----------------
__global__ void cast_all(const float* __restrict__ x, const float* __restrict__ wq,
                         const float* __restrict__ wk, const float* __restrict__ wv,
                         const float* __restrict__ wo, f16* __restrict__ xh,
                         f16* __restrict__ wqh, f16* __restrict__ wkh,
                         f16* __restrict__ wvh, f16* __restrict__ woh) {
  int i = blockIdx.x * blockDim.x + threadIdx.x;
  const float* in;
  f16* out;
  int j = i;
  if (j < 4194304) { in = x; out = xh; }
  else if ((j -= 4194304) < 4194304) { in = wq; out = wqh; }
  else if ((j -= 4194304) < 1048576) { in = wk; out = wkh; }
  else if ((j -= 1048576) < 1048576) { in = wv; out = wvh; }
  else { j -= 1048576; in = wo; out = woh; }
  float4 v = ((const float4*)in)[j];
  f16x4 h;
  h[0] = (f16)v.x; h[1] = (f16)v.y; h[2] = (f16)v.z; h[3] = (f16)v.w;
  *(f16x4*)(out + (size_t)j * 4) = h;
}

// ---------------- GEMM core: C(256 x NF*128) = A(256xK) * B(NF*128 x K)^T, K=4096 ----
// 32x32x16 MFMA (2x FLOP per LDS byte vs 16x16x32), 8 waves 2x4, ring-2 LDS, BK=64,
// one barrier + vmcnt(0) per tile (STAGE(t+1) hides under the tile's MFMAs).
// 3-bit XOR granule swizzle keeps fragment ds_read_b128 conflict-free.
template <int NF>
__device__ __forceinline__ void gemm_core(const f16* __restrict__ Ab,
                                          const f16* __restrict__ Bb,
                                          f16* __restrict__ lds,
                                          f32x16 acc[4][NF]) {
  constexpr int BN = NF * 128;
  constexpr int S = 16384 + BN * 64;  // f16 stride of one ring buffer
  constexpr int BU = BN / 64;         // B granule-chunks per thread
  const int tid = threadIdx.x, ln = tid & 63, wv = tid >> 6;
  const int wr = wv >> 2, wc = wv & 3;
  const int l31 = ln & 31, h32 = ln >> 5;
  const int x7 = l31 & 7;
#pragma unroll
  for (int mi = 0; mi < 4; ++mi)
#pragma unroll
    for (int ni = 0; ni < NF; ++ni)
#pragma unroll
      for (int r = 0; r < 16; ++r) acc[mi][ni][r] = 0.f;

  // staging source offsets (f16 elements): physical granule P -> unswizzled global col
  int sA[4], sB[BU];
#pragma unroll
  for (int u = 0; u < 4; ++u) {
    int P = u * 512 + tid;
    sA[u] = (P >> 3) * 4096 + (((P & 7) ^ ((P >> 3) & 7)) * 8);
  }
#pragma unroll
  for (int u = 0; u < BU; ++u) {
    int P = u * 512 + tid;
    sB[u] = (P >> 3) * 4096 + (((P & 7) ^ ((P >> 3) & 7)) * 8);
  }
  // fragment row bases (f16 index into buffer); row&7 == l31&7 for all frags
  int rA[4], rB[NF];
#pragma unroll
  for (int mi = 0; mi < 4; ++mi) rA[mi] = (wr * 128 + mi * 32 + l31) * 64;
#pragma unroll
  for (int ni = 0; ni < NF; ++ni) rB[ni] = 16384 + (wc * (NF * 32) + ni * 32 + l31) * 64;

#define STAGE(BUF, K0)                                                        \
  {                                                                           \
    _Pragma("unroll") for (int u = 0; u < 4; ++u) {                           \
      gld_lds16(Ab + sA[u] + (K0), lds + (BUF) + (u * 512 + wv * 64) * 8);    \
    }                                                                         \
    _Pragma("unroll") for (int u = 0; u < BU; ++u) {                          \
      gld_lds16(Bb + sB[u] + (K0),                                            \
                lds + (BUF) + 16384 + (u * 512 + wv * 64) * 8);               \
    }                                                                         \
  }

#define TILE_COMPUTE(BUF)                                                     \
  _Pragma("unroll") for (int ks = 0; ks < 4; ++ks) {                          \
    f16x8 af[4];                                                              \
    f16x8 bf[NF];                                                             \
    int gk = ((ks * 2 + h32) ^ x7) * 8;                                       \
    _Pragma("unroll") for (int mi = 0; mi < 4; ++mi) {                        \
      af[mi] = *(const f16x8*)&lds[(BUF) + rA[mi] + gk];                      \
    }                                                                         \
    _Pragma("unroll") for (int ni = 0; ni < NF; ++ni) {                       \
      bf[ni] = *(const f16x8*)&lds[(BUF) + rB[ni] + gk];                      \
    }                                                                         \
    __builtin_amdgcn_s_setprio(1);                                            \
    _Pragma("unroll") for (int mi = 0; mi < 4; ++mi) {                        \
      _Pragma("unroll") for (int ni = 0; ni < NF; ++ni) {                     \
        acc[mi][ni] = __builtin_amdgcn_mfma_f32_32x32x16_f16(                 \
            af[mi], bf[ni], acc[mi][ni], 0, 0, 0);                            \
      }                                                                       \
    }                                                                         \
    __builtin_amdgcn_s_setprio(0);                                            \
  }

#define SYNC()                                                                \
  __builtin_amdgcn_sched_barrier(0);                                          \
  vm0();                                                                      \
  __builtin_amdgcn_s_barrier();                                               \
  __builtin_amdgcn_sched_barrier(0);

  int cur = 0, nxt = S;
  STAGE(cur, 0);
  SYNC();
#pragma unroll 1
  for (int t = 0; t < 63; ++t) {
    STAGE(nxt, (t + 1) * 64);
    TILE_COMPUTE(cur);
    SYNC();
    int tmp = cur; cur = nxt; nxt = tmp;
  }
  TILE_COMPUTE(cur);

#undef STAGE
#undef TILE_COMPUTE
#undef SYNC
}

// ---------------- fused QKV projection ----------------
// 256 blocks (16 M x 16 N of 384), one per CU, single round. wqh/wkh/wvh are contiguous
// in the workspace -> B panels read linearly from wqh even when straddling Q/K/V.
__global__ __launch_bounds__(512, 2) void gemm_qkv(
    const f16* __restrict__ xh, const f16* __restrict__ wcat,
    f16* __restrict__ qh, f16* __restrict__ kh, f16* __restrict__ vt) {
  __shared__ __align__(16) f16 lds[81920];  // 160 KiB: 2 x (A 32K + B 48K)
  const int id = blockIdx.x;
  const int swz = (id & 7) * 32 + (id >> 3);  // 256 = 8 XCD * 32 (bijective)
  const int bx = swz & 15, by = swz >> 4;
  f32x16 acc[4][3];
  gemm_core<3>(xh + (size_t)by * 256 * 4096, wcat + (size_t)bx * 384 * 4096, lds, acc);
  const int tid = threadIdx.x, ln = tid & 63, wv = tid >> 6;
  const int wr = wv >> 2, wc = wv & 3;
  const int l31 = ln & 31, h32 = ln >> 5;
#pragma unroll
  for (int mi = 0; mi < 4; ++mi)
#pragma unroll
    for (int ni = 0; ni < 3; ++ni) {
      int gc = bx * 384 + wc * 96 + ni * 32;  // frag col base (wave-uniform)
#pragma unroll
      for (int g = 0; g < 4; ++g) {
        int row = by * 256 + wr * 128 + mi * 32 + h32 * 4 + g * 8;  // token of reg 4g
        if (gc < 4096) {
#pragma unroll
          for (int r2 = 0; r2 < 4; ++r2)
            qh[(size_t)(row + r2) * 4096 + gc + l31] = (f16)acc[mi][ni][g * 4 + r2];
        } else if (gc < 5120) {
#pragma unroll
          for (int r2 = 0; r2 < 4; ++r2)
            kh[(size_t)(row + r2) * 1024 + (gc - 4096) + l31] = (f16)acc[mi][ni][g * 4 + r2];
        } else {
          f16x4 v4;
#pragma unroll
          for (int r2 = 0; r2 < 4; ++r2) v4[r2] = (f16)acc[mi][ni][g * 4 + r2];
          int vcol = gc + l31 - 5120;
          int kv = vcol >> 7, d = vcol & 127;
          int bbv = row >> 11, sl = row & 2047;  // 4 consecutive tokens, same batch
          *(f16x4*)&vt[(((size_t)bbv * 8 + kv) * 128 + d) * 2048 + sl] = v4;
        }
      }
    }
}

// ---------------- RoPE in-place on Q and K (16B per thread) ----------------
__global__ void rope_qk(f16* __restrict__ qh, f16* __restrict__ kh,
                        const float* __restrict__ fc, const float* __restrict__ fs) {
  int i = blockIdx.x * blockDim.x + threadIdx.x;  // granule = 8 f16 = 4 rot pairs
  const int QG = 4096 * 32 * 16;
  f16* ptr;
  int sl, p0;
  if (i < QG) {
    int g = i & 15, head = (i >> 4) & 31, tok = i >> 9;
    sl = tok & 2047; p0 = g * 4;
    ptr = qh + (size_t)tok * 4096 + head * 128 + g * 8;
  } else {
    int j = i - QG;
    int g = j & 15, head = (j >> 4) & 7, tok = j >> 7;
    sl = tok & 2047; p0 = g * 4;
    ptr = kh + (size_t)tok * 1024 + head * 128 + g * 8;
  }
  f16x8 v = *(f16x8*)ptr;
  float4 c = *(const float4*)&fc[sl * 64 + p0];
  float4 s = *(const float4*)&fs[sl * 64 + p0];
  f16x8 o;
  o[0] = (f16)((float)v[0] * c.x - (float)v[1] * s.x);
  o[1] = (f16)((float)v[0] * s.x + (float)v[1] * c.x);
  o[2] = (f16)((float)v[2] * c.y - (float)v[3] * s.y);
  o[3] = (f16)((float)v[2] * s.y + (float)v[3] * c.y);
  o[4] = (f16)((float)v[4] * c.z - (float)v[5] * s.z);
  o[5] = (f16)((float)v[4] * s.z + (float)v[5] * c.z);
  o[6] = (f16)((float)v[6] * c.w - (float)v[7] * s.w);
  o[7] = (f16)((float)v[6] * s.w + (float)v[7] * c.w);
  *(f16x8*)ptr = o;
}

// ---------------- causal GQA flash attention (transposed S/O formulation) ----------------
// grid (32 qtiles, 32 heads, 2 batch), 4 waves, each wave a 16-query strip (q = lane&15).
// S^T = K Q^T  (lane owns query col q=c16 -> in-lane softmax), O^T = V^T P^T.
// Pipelined single-buffer staging: the drain for each K/V tile lands AFTER a compute
// phase instead of before it. K and V are consumed in different halves of the tile:
//   V(t) drains after QK^T(t)+softmax;  K(t+1) is issued there and drains after PV(t);
//   V(t+1) is issued after the post-PV barrier and drains after QK^T(t+1).
// Same 2 barriers/tile and 40KB LDS as the verified base; only the wait points move.
__global__ __launch_bounds__(256, 4) void attn(
    const f16* __restrict__ qh, const f16* __restrict__ kh,
    const f16* __restrict__ vt, f16* __restrict__ ao) {
  __shared__ __align__(16) f16 Kl[64 * 128];   // [s][d], granule-swizzled g^(s&15)
  __shared__ __align__(16) f16 Vl[128 * 64];   // [d][s], granule-swizzled g^(d&7)
  __shared__ __align__(16) f16 Pl[4][16 * 64]; // per-wave P [q][k], granule-swizzled g^(q&7)
  const int qt = 31 - blockIdx.x;  // longest blocks dispatch first
  const int h = blockIdx.y, bb = blockIdx.z;
  const int kvh = h >> 2;
  const int tid = threadIdx.x, ln = tid & 63, wv = tid >> 6;
  const int quad = ln >> 4, c16 = ln & 15;

#define ISSUE_K(T)                                                            \
  _Pragma("unroll") for (int c = 0; c < 4; ++c) {                             \
    int chunk = wv * 4 + c;                                                   \
    int krow = chunk * 4 + (ln >> 4);                                         \
    int kg = (ln & 15) ^ (krow & 15);                                         \
    gld_lds16(&kh[((size_t)(bb * 2048 + (T) * 64 + krow)) * 1024 +            \
                  kvh * 128 + kg * 8],                                        \
              &Kl[chunk * 512]);                                              \
  }
#define ISSUE_V(T)                                                            \
  _Pragma("unroll") for (int c = 0; c < 4; ++c) {                             \
    int chunk = wv * 4 + c;                                                   \
    int vrow = chunk * 8 + (ln >> 3);                                         \
    int vg = (ln & 7) ^ (vrow & 7);                                           \
    gld_lds16(&vt[(((size_t)bb * 8 + kvh) * 128 + vrow) * 2048 +              \
                  (T) * 64 + vg * 8],                                         \
              &Vl[chunk * 512]);                                              \
  }
#define DRAIN_BAR()                                                           \
  __builtin_amdgcn_sched_barrier(0);                                          \
  vm0();                                                                      \
  __builtin_amdgcn_s_barrier();                                               \
  __builtin_amdgcn_sched_barrier(0);

  // Q fragment (A/B layout identical): lane holds Q[q=strip row c16][d = ks*32+quad*8+j]
  f16x8 Qf[4];
  {
    size_t qbase = ((size_t)(bb * 2048 + qt * 64 + wv * 16 + c16)) * 4096 + h * 128;
#pragma unroll
    for (int ks = 0; ks < 4; ++ks)
      Qf[ks] = *(const f16x8*)&qh[qbase + ks * 32 + quad * 8];
  }
  float m_run = -INFINITY, l_run = 0.f;
  f32x4 Ot[8];  // O^T tiles over d; lane col = q
#pragma unroll
  for (int n = 0; n < 8; ++n) { f32x4 z = {0.f, 0.f, 0.f, 0.f}; Ot[n] = z; }
  const float scale = 0.08838834764831843f;  // 1/sqrt(128)
  const int qg = qt * 64 + wv * 16 + c16;    // this lane's global query index
  const int swp = ((quad ^ (c16 & 7)) * 8);         // Pl read swizzle, ks=0
  const int swp1 = (((4 + quad) ^ (c16 & 7)) * 8);  // ks=1

  // prologue: tile 0 fully staged
  ISSUE_K(0);
  ISSUE_V(0);
  DRAIN_BAR();

  for (int t = 0; t <= qt; ++t) {
    // S^T(64x16 per wave): Sa[tn] = K-tile(tn) x Q^T; D[k'=quad*4+r][q=c16]
    f32x4 Sa[4];
#pragma unroll
    for (int tn = 0; tn < 4; ++tn) {
      f32x4 z = {0.f, 0.f, 0.f, 0.f};
      Sa[tn] = z;
      __builtin_amdgcn_s_setprio(1);
#pragma unroll
      for (int ks = 0; ks < 4; ++ks) {
        f16x8 kf = *(const f16x8*)&Kl[(tn * 16 + c16) * 128 + (((ks * 4 + quad) ^ c16) * 8)];
        Sa[tn] = __builtin_amdgcn_mfma_f32_16x16x32_f16(kf, Qf[ks], Sa[tn], 0, 0, 0);
      }
      __builtin_amdgcn_s_setprio(0);
    }

    // scale + causal mask (diagonal tile only)
#pragma unroll
    for (int tn = 0; tn < 4; ++tn)
#pragma unroll
      for (int r = 0; r < 4; ++r) Sa[tn][r] *= scale;
    if (t == qt) {
#pragma unroll
      for (int tn = 0; tn < 4; ++tn) {
        int kbase2 = t * 64 + tn * 16 + quad * 4;
#pragma unroll
        for (int r = 0; r < 4; ++r)
          if (kbase2 + r > qg) Sa[tn][r] = -INFINITY;
      }
    }

    // online softmax: per-lane (one q per lane), 2 shuffles per reduction
    float mm = -INFINITY;
#pragma unroll
    for (int tn = 0; tn < 4; ++tn)
#pragma unroll
      for (int r = 0; r < 4; ++r) mm = fmaxf(mm, Sa[tn][r]);
    mm = fmaxf(mm, __shfl_xor(mm, 16, 64));
    mm = fmaxf(mm, __shfl_xor(mm, 32, 64));
    float mn = fmaxf(m_run, mm);
    float alpha = __expf(m_run - mn);
    m_run = mn;
    float rsum = 0.f;
#pragma unroll
    for (int tn = 0; tn < 4; ++tn)
#pragma unroll
      for (int r = 0; r < 4; ++r) {
        float p = __expf(Sa[tn][r] - mn);
        Sa[tn][r] = p;
        rsum += p;
      }
    rsum += __shfl_xor(rsum, 16, 64);
    rsum += __shfl_xor(rsum, 32, 64);
    l_run = l_run * alpha + rsum;

    // P^T (C-layout) -> Pl[q][k] (8B packed, swizzled)
#pragma unroll
    for (int tn = 0; tn < 4; ++tn) {
      f16x4 pk;
#pragma unroll
      for (int r = 0; r < 4; ++r) pk[r] = (f16)Sa[tn][r];
      int g = tn * 2 + (quad >> 1);
      *(f16x4*)&Pl[wv][c16 * 64 + ((g ^ (c16 & 7)) * 8) + (quad & 1) * 4] = pk;
    }

    // rescale O (alpha is a per-lane scalar)
#pragma unroll
    for (int n = 0; n < 8; ++n)
#pragma unroll
      for (int r = 0; r < 4; ++r) Ot[n][r] *= alpha;

    // V(t) drain (issued >=1 phase ago: hidden) + Kl-free barrier
    DRAIN_BAR();
    if (t < qt) ISSUE_K(t + 1);  // overlaps with PV(t)

    lgkm0();  // P writes -> P reads (same wave)

    // O^T += V^T P^T : A=V^T[d][k] frags, B=P^T (= rows of Pl[q][k])
    {
      f16x8 pf0 = *(const f16x8*)&Pl[wv][c16 * 64 + swp];
      f16x8 pf1 = *(const f16x8*)&Pl[wv][c16 * 64 + swp1];
      __builtin_amdgcn_s_setprio(1);
#pragma unroll
      for (int n = 0; n < 8; ++n) {
        int rowv = (n * 16 + c16) * 64;
        f16x8 vf0 = *(const f16x8*)&Vl[rowv + swp];
        Ot[n] = __builtin_amdgcn_mfma_f32_16x16x32_f16(vf0, pf0, Ot[n], 0, 0, 0);
        f16x8 vf1 = *(const f16x8*)&Vl[rowv + swp1];
        Ot[n] = __builtin_amdgcn_mfma_f32_16x16x32_f16(vf1, pf1, Ot[n], 0, 0, 0);
      }
      __builtin_amdgcn_s_setprio(0);
    }

    // K(t+1) drain (hidden under PV) + Vl-free barrier
    DRAIN_BAR();
    if (t < qt) ISSUE_V(t + 1);  // overlaps with QK^T(t+1)
  }

  // epilogue: O = O^T normalized; lane writes 4 contiguous d per tile (8B stores)
  float inv = 1.0f / l_run;
  size_t token = (size_t)(bb * 2048 + qt * 64 + wv * 16 + c16);
#pragma unroll
  for (int n = 0; n < 8; ++n) {
    f16x4 o;
#pragma unroll
    for (int r = 0; r < 4; ++r) o[r] = (f16)(Ot[n][r] * inv);
    *(f16x4*)&ao[token * 4096 + h * 128 + n * 16 + quad * 4] = o;
  }
#undef ISSUE_K
#undef ISSUE_V
#undef DRAIN_BAR
}

// ---------------- output projection: out = ao @ wo^T (fp32 out) ----------------
__global__ __launch_bounds__(512, 2) void gemm_out(
    const f16* __restrict__ ao, const f16* __restrict__ woh, float* __restrict__ out) {
  __shared__ __align__(16) f16 lds[65536];  // 128 KiB: 2 x (A 32K + B 32K)
  const int id = blockIdx.x;
  const int swz = (id & 7) * 32 + (id >> 3);  // 256 = 8 XCD * 32 (bijective)
  const int bx = swz & 15, by = swz >> 4;
  f32x16 acc[4][2];
  gemm_core<2>(ao + (size_t)by * 256 * 4096, woh + (size_t)bx * 256 * 4096, lds, acc);
  const int tid = threadIdx.x, ln = tid & 63, wv = tid >> 6;
  const int wr = wv >> 2, wc = wv & 3;
  const int l31 = ln & 31, h32 = ln >> 5;
#pragma unroll
  for (int mi = 0; mi < 4; ++mi)
#pragma unroll
    for (int ni = 0; ni < 2; ++ni) {
      int col = bx * 256 + wc * 64 + ni * 32 + l31;
#pragma unroll
      for (int g = 0; g < 4; ++g) {
        int row = by * 256 + wr * 128 + mi * 32 + h32 * 4 + g * 8;
#pragma unroll
        for (int r2 = 0; r2 < 4; ++r2)
          out[(size_t)(row + r2) * 4096 + col] = acc[mi][ni][g * 4 + r2];
      }
    }
}

// ---------------- launch ----------------
extern "C" void kernel_launch(void* const* d_in, const int* in_sizes, int n_in,
                              void* d_out, int out_size, void* d_ws, size_t ws_size,
                              hipStream_t stream) {
  const float* x  = (const float*)d_in[0];
  const float* wq = (const float*)d_in[1];
  const float* wk = (const float*)d_in[2];
  const float* wv = (const float*)d_in[3];
  const float* wo = (const float*)d_in[4];
  const float* fc = (const float*)d_in[5];
  const float* fs = (const float*)d_in[6];
  float* out = (float*)d_out;

  char* ws = (char*)d_ws;
  f16* xh  = (f16*)(ws + 0);          // 32 MiB: x fp16 [4096][4096]
  f16* wqh = (f16*)(ws + 33554432);   // 32 MiB (wqh,wkh,wvh contiguous = wcat[6144][4096])
  f16* wkh = (f16*)(ws + 67108864);   // 8 MiB
  f16* wvh = (f16*)(ws + 75497472);   // 8 MiB
  f16* woh = (f16*)(ws + 83886080);   // 32 MiB
  f16* qh  = (f16*)(ws + 117440512);  // 32 MiB: Q [4096][4096]
  f16* kh  = (f16*)(ws + 150994944);  // 8 MiB:  K [4096][1024]
  f16* vt  = (f16*)(ws + 159383552);  // 8 MiB:  V^T [2][8][128][2048]
  f16* ao  = (f16*)(ws + 167772160);  // 32 MiB: attn out [4096][4096]

  cast_all<<<57344, 256, 0, stream>>>(x, wq, wk, wv, wo, xh, wqh, wkh, wvh, woh);
  gemm_qkv<<<256, 512, 0, stream>>>(xh, wqh, qh, kh, vt);
  rope_qk<<<10240, 256, 0, stream>>>(qh, kh, fc, fs);
  attn<<<dim3(32, 32, 2), 256, 0, stream>>>(qh, kh, vt, ao);
  gemm_out<<<256, 512, 0, stream>>>(ao, woh, out);
}